// Round 1
// baseline (753.137 us; speedup 1.0000x reference)
//
#include <hip/hip_runtime.h>

// EdgeConv fused GNN: msg-MLP (E×[160→128→128→64]+LN) → segment_sum → upd-MLP (N×[128→128→128→64]+LN)+res
// Strategy: bf16 MFMA (16x16x32) with fp32 accum; weights pre-transposed to bf16 [n][k] in d_ws.
// Per block: 128-row tile, 256 threads (4 waves), LDS buffer rotation, LN in LDS, atomic scatter for agg.

typedef __attribute__((ext_vector_type(8))) short s16x8;   // 8 bf16 (4 VGPRs) — MFMA A/B frag
typedef __attribute__((ext_vector_type(4))) float f32x4;   // MFMA C/D frag
typedef __attribute__((ext_vector_type(4))) unsigned short u16x4;

__device__ __forceinline__ unsigned short f2bf(float x) {
  union { float f; unsigned u; } v; v.f = x;
  unsigned r = v.u + 0x7fffu + ((v.u >> 16) & 1u);   // RNE
  return (unsigned short)(r >> 16);
}

// ---------------- weight transpose+convert: wts[off + n*K + k] = bf16(src[k*N + n]) ----------------
// layout (ushort elems): mW1t @0 (128x160), mW2t @20480 (128x128), mW3t @36864 (64x128),
//                        uW1t @45056 (128x128), uW2t @61440 (128x128), uW3t @77824 (64x128); total 86016
__global__ __launch_bounds__(256) void wconv(
    const float* __restrict__ mW1, const float* __restrict__ mW2, const float* __restrict__ mW3,
    const float* __restrict__ uW1, const float* __restrict__ uW2, const float* __restrict__ uW3,
    unsigned short* __restrict__ wts) {
  int t = blockIdx.x * 256 + threadIdx.x;
  const float* src; int K, N, off;
  if      (t < 20480) { src = mW1; K = 160; N = 128; off = 0;     }
  else if (t < 36864) { src = mW2; K = 128; N = 128; off = 20480; }
  else if (t < 45056) { src = mW3; K = 128; N = 64;  off = 36864; }
  else if (t < 61440) { src = uW1; K = 128; N = 128; off = 45056; }
  else if (t < 77824) { src = uW2; K = 128; N = 128; off = 61440; }
  else if (t < 86016) { src = uW3; K = 128; N = 64;  off = 77824; }
  else return;
  int local = t - off;
  int n = local / K, k = local - n * K;
  wts[off + n * K + k] = f2bf(src[k * N + n]);
}

// ---------------- shared MFMA layer: D[128 x 16*NT] = A[128 x 32*KSTEPS] @ B ----------------
// wave w owns rows [32w, 32w+32). A,B in LDS bf16: A row-major stride ASTR, B = Wt (n-major) stride BSTR.
template<int KSTEPS, int NT, int ASTR, int BSTR>
__device__ __forceinline__ void do_layer(const unsigned short* A, const unsigned short* B,
                                         f32x4 (&acc)[2][8], int w, int quad, int l15) {
  f32x4 z = {0.f, 0.f, 0.f, 0.f};
  #pragma unroll
  for (int i = 0; i < 2; i++)
    #pragma unroll
    for (int j = 0; j < NT; j++) acc[i][j] = z;
  #pragma unroll
  for (int kb = 0; kb < KSTEPS; kb++) {
    s16x8 a0 = *(const s16x8*)&A[(w * 32 + l15) * ASTR + kb * 32 + quad * 8];
    s16x8 a1 = *(const s16x8*)&A[(w * 32 + 16 + l15) * ASTR + kb * 32 + quad * 8];
    #pragma unroll
    for (int nt = 0; nt < NT; nt++) {
      s16x8 b = *(const s16x8*)&B[(nt * 16 + l15) * BSTR + kb * 32 + quad * 8];
      acc[0][nt] = __builtin_amdgcn_mfma_f32_16x16x32_bf16(a0, b, acc[0][nt], 0, 0, 0);
      acc[1][nt] = __builtin_amdgcn_mfma_f32_16x16x32_bf16(a1, b, acc[1][nt], 0, 0, 0);
    }
  }
}

// bias + ReLU + cvt bf16 + store to LDS (next layer's A tile)
template<int NT, int DSTR>
__device__ __forceinline__ void store_relu_bf16(f32x4 (&acc)[2][8], const float* __restrict__ bias,
                                                unsigned short* dst, int w, int quad, int l15) {
  #pragma unroll
  for (int nt = 0; nt < NT; nt++) {
    float b = bias[nt * 16 + l15];
    #pragma unroll
    for (int i = 0; i < 2; i++) {
      int row = w * 32 + i * 16 + quad * 4;
      #pragma unroll
      for (int r = 0; r < 4; r++) {
        float v = acc[i][nt][r] + b;
        v = v > 0.f ? v : 0.f;
        dst[(row + r) * DSTR + nt * 16 + l15] = f2bf(v);
      }
    }
  }
}

// bias (no relu) fp32 store to LN buffer (stride 65 floats, conflict-padded)
__device__ __forceinline__ void store_preln(f32x4 (&acc)[2][8], const float* __restrict__ bias,
                                            float* lnbuf, int w, int quad, int l15) {
  #pragma unroll
  for (int nt = 0; nt < 4; nt++) {
    float b = bias[nt * 16 + l15];
    #pragma unroll
    for (int i = 0; i < 2; i++)
      #pragma unroll
      for (int r = 0; r < 4; r++)
        lnbuf[(w * 32 + i * 16 + quad * 4 + r) * 65 + nt * 16 + l15] = acc[i][nt][r] + b;
  }
}

// ---------------- message MLP kernel: 128 edges / block ----------------
__global__ __launch_bounds__(256) void msg_kernel(
    const float* __restrict__ h, const int* __restrict__ ei, const float* __restrict__ ea,
    const unsigned short* __restrict__ wts,
    const float* __restrict__ mb1, const float* __restrict__ mb2, const float* __restrict__ mb3,
    const float* __restrict__ mg, const float* __restrict__ mbt,
    float* __restrict__ msg_out, float* __restrict__ agg, int E, int Nn) {
  // buf0 43008B: X(128x168 bf16) -> W2t(128x136) -> W3t(64x136)
  // buf1 43008B: W1t(128x168)    -> h2(128x136)
  // buf2 34816B: h1(128x136)     -> lnbuf(128x65 f32 = 33280)
  __shared__ __align__(16) unsigned char smem[43008 + 43008 + 34816 + 1024];
  unsigned short* buf0 = (unsigned short*)smem;
  unsigned short* buf1 = (unsigned short*)(smem + 43008);
  unsigned short* buf2 = (unsigned short*)(smem + 86016);
  float* stats = (float*)(smem + 120832);
  float* lnbuf = (float*)buf2;

  const int tid = threadIdx.x;
  const int w = tid >> 6, lane = tid & 63, quad = lane >> 4, l15 = lane & 15;
  const int e0 = blockIdx.x * 128;
  const int* srcI = ei;
  const int* dstI = ei + E;

  // ---- stage X = [h[src] | h[dst] | edge_attr] -> buf0 bf16, stride 168
  for (int idx = tid; idx < 128 * 40; idx += 256) {
    int er = idx / 40, seg = idx - er * 40;    // 40 float4 chunks per edge
    int e = e0 + er;
    u16x4 o = {0, 0, 0, 0};
    if (e < E) {
      const float* p;
      if (seg < 16)      p = h + (size_t)srcI[e] * 64 + seg * 4;
      else if (seg < 32) p = h + (size_t)dstI[e] * 64 + (seg - 16) * 4;
      else               p = ea + (size_t)e * 32 + (seg - 32) * 4;
      float4 v = *(const float4*)p;
      o[0] = f2bf(v.x); o[1] = f2bf(v.y); o[2] = f2bf(v.z); o[3] = f2bf(v.w);
    }
    *(u16x4*)&buf0[er * 168 + seg * 4] = o;
  }
  // ---- stage W1t (128 rows x 160) -> buf1 stride 168
  for (int idx = tid; idx < 128 * 20; idx += 256) {
    int r = idx / 20, s = idx - r * 20;
    *(s16x8*)&buf1[r * 168 + s * 8] = *(const s16x8*)&wts[r * 160 + s * 8];
  }
  __syncthreads();

  f32x4 acc[2][8];
  // L1: 160 -> 128
  do_layer<5, 8, 168, 168>(buf0, buf1, acc, w, quad, l15);
  store_relu_bf16<8, 136>(acc, mb1, buf2, w, quad, l15);
  __syncthreads();
  // stage W2t -> buf0 (X dead)
  for (int idx = tid; idx < 128 * 16; idx += 256) {
    int r = idx >> 4, s = idx & 15;
    *(s16x8*)&buf0[r * 136 + s * 8] = *(const s16x8*)&wts[20480 + r * 128 + s * 8];
  }
  __syncthreads();
  // L2: 128 -> 128
  do_layer<4, 8, 136, 136>(buf2, buf0, acc, w, quad, l15);
  store_relu_bf16<8, 136>(acc, mb2, buf1, w, quad, l15);   // W1t dead
  __syncthreads();
  // stage W3t -> buf0 (W2t dead)
  for (int idx = tid; idx < 64 * 16; idx += 256) {
    int r = idx >> 4, s = idx & 15;
    *(s16x8*)&buf0[r * 136 + s * 8] = *(const s16x8*)&wts[36864 + r * 128 + s * 8];
  }
  __syncthreads();
  // L3: 128 -> 64 (no relu), fp32 -> lnbuf (h1 dead)
  do_layer<4, 4, 136, 136>(buf1, buf0, acc, w, quad, l15);
  store_preln(acc, mb3, lnbuf, w, quad, l15);
  __syncthreads();

  // ---- LayerNorm stats: one thread per row
  if (tid < 128) {
    float s = 0.f, sq = 0.f;
    #pragma unroll
    for (int c = 0; c < 64; c++) { float x = lnbuf[tid * 65 + c]; s += x; sq += x * x; }
    float mu = s * (1.f / 64.f);
    float var = sq * (1.f / 64.f) - mu * mu;
    stats[2 * tid] = mu;
    stats[2 * tid + 1] = rsqrtf(var + 1e-5f);
  }
  __syncthreads();

  // ---- write msg (coalesced) + atomic scatter into agg[dst]
  for (int idx = tid; idx < 128 * 64; idx += 256) {
    int r = idx >> 6, c = idx & 63;
    int e = e0 + r;
    if (e < E) {
      float mu = stats[2 * r], rstd = stats[2 * r + 1];
      float v = (lnbuf[r * 65 + c] - mu) * rstd * mg[c] + mbt[c];
      msg_out[(size_t)e * 64 + c] = v;
      atomicAdd(agg + (size_t)dstI[e] * 64 + c, v);
    }
  }
}

// ---------------- update MLP kernel: 128 nodes / block ----------------
__global__ __launch_bounds__(256) void upd_kernel(
    const float* __restrict__ h, const float* __restrict__ agg,
    const unsigned short* __restrict__ wts,
    const float* __restrict__ ub1, const float* __restrict__ ub2, const float* __restrict__ ub3,
    const float* __restrict__ ug, const float* __restrict__ ubt,
    float* __restrict__ h_new, int Nn) {
  // buf0: X(128x136) -> W2t -> W3t ; buf1: uW1t -> h2 ; buf2: h1 -> lnbuf
  __shared__ __align__(16) unsigned char smem[34816 * 3 + 1024];
  unsigned short* buf0 = (unsigned short*)smem;
  unsigned short* buf1 = (unsigned short*)(smem + 34816);
  unsigned short* buf2 = (unsigned short*)(smem + 69632);
  float* stats = (float*)(smem + 104448);
  float* lnbuf = (float*)buf2;

  const int tid = threadIdx.x;
  const int w = tid >> 6, lane = tid & 63, quad = lane >> 4, l15 = lane & 15;
  const int n0 = blockIdx.x * 128;

  // ---- stage X = [h | agg] -> buf0 bf16, stride 136
  for (int idx = tid; idx < 128 * 32; idx += 256) {
    int r = idx >> 5, seg = idx & 31;
    int n = n0 + r;
    u16x4 o = {0, 0, 0, 0};
    if (n < Nn) {
      const float* p = (seg < 16) ? h + (size_t)n * 64 + seg * 4
                                  : agg + (size_t)n * 64 + (seg - 16) * 4;
      float4 v = *(const float4*)p;
      o[0] = f2bf(v.x); o[1] = f2bf(v.y); o[2] = f2bf(v.z); o[3] = f2bf(v.w);
    }
    *(u16x4*)&buf0[r * 136 + seg * 4] = o;
  }
  for (int idx = tid; idx < 128 * 16; idx += 256) {
    int r = idx >> 4, s = idx & 15;
    *(s16x8*)&buf1[r * 136 + s * 8] = *(const s16x8*)&wts[45056 + r * 128 + s * 8];
  }
  __syncthreads();

  f32x4 acc[2][8];
  do_layer<4, 8, 136, 136>(buf0, buf1, acc, w, quad, l15);
  store_relu_bf16<8, 136>(acc, ub1, buf2, w, quad, l15);
  __syncthreads();
  for (int idx = tid; idx < 128 * 16; idx += 256) {
    int r = idx >> 4, s = idx & 15;
    *(s16x8*)&buf0[r * 136 + s * 8] = *(const s16x8*)&wts[61440 + r * 128 + s * 8];
  }
  __syncthreads();
  do_layer<4, 8, 136, 136>(buf2, buf0, acc, w, quad, l15);
  store_relu_bf16<8, 136>(acc, ub2, buf1, w, quad, l15);
  __syncthreads();
  for (int idx = tid; idx < 64 * 16; idx += 256) {
    int r = idx >> 4, s = idx & 15;
    *(s16x8*)&buf0[r * 136 + s * 8] = *(const s16x8*)&wts[77824 + r * 128 + s * 8];
  }
  __syncthreads();
  do_layer<4, 4, 136, 136>(buf1, buf0, acc, w, quad, l15);
  store_preln(acc, ub3, lnbuf, w, quad, l15);
  __syncthreads();

  if (tid < 128) {
    float s = 0.f, sq = 0.f;
    #pragma unroll
    for (int c = 0; c < 64; c++) { float x = lnbuf[tid * 65 + c]; s += x; sq += x * x; }
    float mu = s * (1.f / 64.f);
    float var = sq * (1.f / 64.f) - mu * mu;
    stats[2 * tid] = mu;
    stats[2 * tid + 1] = rsqrtf(var + 1e-5f);
  }
  __syncthreads();

  for (int idx = tid; idx < 128 * 64; idx += 256) {
    int r = idx >> 6, c = idx & 63;
    int n = n0 + r;
    if (n < Nn) {
      float mu = stats[2 * r], rstd = stats[2 * r + 1];
      float v = (lnbuf[r * 65 + c] - mu) * rstd * ug[c] + ubt[c] + h[(size_t)n * 64 + c];
      h_new[(size_t)n * 64 + c] = v;
    }
  }
}

extern "C" void kernel_launch(void* const* d_in, const int* in_sizes, int n_in,
                              void* d_out, int out_size, void* d_ws, size_t ws_size,
                              hipStream_t stream) {
  const float* h   = (const float*)d_in[0];
  const int*   ei  = (const int*)d_in[1];
  const float* ea  = (const float*)d_in[2];
  const float* mW1 = (const float*)d_in[3];
  const float* mb1 = (const float*)d_in[4];
  const float* mW2 = (const float*)d_in[5];
  const float* mb2 = (const float*)d_in[6];
  const float* mW3 = (const float*)d_in[7];
  const float* mb3 = (const float*)d_in[8];
  const float* mg  = (const float*)d_in[9];
  const float* mbt = (const float*)d_in[10];
  const float* uW1 = (const float*)d_in[11];
  const float* ub1 = (const float*)d_in[12];
  const float* uW2 = (const float*)d_in[13];
  const float* ub2 = (const float*)d_in[14];
  const float* uW3 = (const float*)d_in[15];
  const float* ub3 = (const float*)d_in[16];
  const float* ug  = (const float*)d_in[17];
  const float* ubt = (const float*)d_in[18];

  const int N = in_sizes[0] / 64;
  const int E = in_sizes[2] / 32;

  float* agg = (float*)d_ws;                                           // N*64 f32
  unsigned short* wts = (unsigned short*)((char*)d_ws + (size_t)N * 64 * sizeof(float));

  float* h_new = (float*)d_out;
  float* msg   = (float*)d_out + (size_t)N * 64;

  hipMemsetAsync(agg, 0, (size_t)N * 64 * sizeof(float), stream);
  wconv<<<dim3((86016 + 255) / 256), dim3(256), 0, stream>>>(mW1, mW2, mW3, uW1, uW2, uW3, wts);
  msg_kernel<<<dim3((E + 127) / 128), dim3(256), 0, stream>>>(
      h, ei, ea, wts, mb1, mb2, mb3, mg, mbt, msg, agg, E, N);
  upd_kernel<<<dim3((N + 127) / 128), dim3(256), 0, stream>>>(
      h, agg, wts, ub1, ub2, ub3, ug, ubt, h_new, N);
}

// Round 2
// 671.193 us; speedup vs baseline: 1.1221x; 1.1221x over previous
//
#include <hip/hip_runtime.h>

// EdgeConv fused GNN: msg-MLP (E×[160→128→128→64]+LN) → segment_sum → upd-MLP (N×[128→128→128→64]+LN)+res
// R2: occupancy fix. Weights read straight from global (L1/L2-resident) instead of LDS staging;
// 64-row tiles; LDS ~39KB → 4 blocks/CU (16 waves/CU, 50% occ) vs R1's 1 block/CU (11%).
// bf16 MFMA 16x16x32, fp32 accum; weights pre-transposed to bf16 [n][k] in d_ws by wconv.

typedef __attribute__((ext_vector_type(8))) short s16x8;   // 8 bf16 (4 VGPRs) — MFMA A/B frag
typedef __attribute__((ext_vector_type(4))) float f32x4;   // MFMA C/D frag
typedef __attribute__((ext_vector_type(4))) unsigned short u16x4;

__device__ __forceinline__ unsigned short f2bf(float x) {
  union { float f; unsigned u; } v; v.f = x;
  unsigned r = v.u + 0x7fffu + ((v.u >> 16) & 1u);   // RNE
  return (unsigned short)(r >> 16);
}

// ---------------- weight transpose+convert: wts[off + n*K + k] = bf16(src[k*N + n]) ----------------
// layout (ushort elems): mW1t @0 (128x160), mW2t @20480 (128x128), mW3t @36864 (64x128),
//                        uW1t @45056 (128x128), uW2t @61440 (128x128), uW3t @77824 (64x128); total 86016
__global__ __launch_bounds__(256) void wconv(
    const float* __restrict__ mW1, const float* __restrict__ mW2, const float* __restrict__ mW3,
    const float* __restrict__ uW1, const float* __restrict__ uW2, const float* __restrict__ uW3,
    unsigned short* __restrict__ wts) {
  int t = blockIdx.x * 256 + threadIdx.x;
  const float* src; int K, N, off;
  if      (t < 20480) { src = mW1; K = 160; N = 128; off = 0;     }
  else if (t < 36864) { src = mW2; K = 128; N = 128; off = 20480; }
  else if (t < 45056) { src = mW3; K = 128; N = 64;  off = 36864; }
  else if (t < 61440) { src = uW1; K = 128; N = 128; off = 45056; }
  else if (t < 77824) { src = uW2; K = 128; N = 128; off = 61440; }
  else if (t < 86016) { src = uW3; K = 128; N = 64;  off = 77824; }
  else return;
  int local = t - off;
  int n = local / K, k = local - n * K;
  wts[off + n * K + k] = f2bf(src[k * N + n]);
}

// ---------------- MFMA layer: wave w computes rows [16w,16w+16) x (16*NT cols) ----------------
// A in LDS (row-major, stride ASTR ushorts); B read from GLOBAL wts (n-major, stride K) — L1/L2 hit.
template<int KSTEPS, int NT, int ASTR, int K>
__device__ __forceinline__ void do_layer(const unsigned short* A,
                                         const unsigned short* __restrict__ Bg,
                                         f32x4 (&acc)[8], int w, int quad, int l15) {
  f32x4 z = {0.f, 0.f, 0.f, 0.f};
  #pragma unroll
  for (int j = 0; j < NT; j++) acc[j] = z;
  #pragma unroll
  for (int kb = 0; kb < KSTEPS; kb++) {
    s16x8 a = *(const s16x8*)&A[(w * 16 + l15) * ASTR + kb * 32 + quad * 8];
    #pragma unroll
    for (int nt = 0; nt < NT; nt++) {
      s16x8 b = *(const s16x8*)&Bg[(nt * 16 + l15) * K + kb * 32 + quad * 8];
      acc[nt] = __builtin_amdgcn_mfma_f32_16x16x32_bf16(a, b, acc[nt], 0, 0, 0);
    }
  }
}

// bias + ReLU + cvt bf16 + store to LDS (next layer's A tile). C/D map: row=quad*4+r, col=nt*16+l15.
template<int NT, int DSTR>
__device__ __forceinline__ void store_relu_bf16(f32x4 (&acc)[8], const float* __restrict__ bias,
                                                unsigned short* dst, int w, int quad, int l15) {
  #pragma unroll
  for (int nt = 0; nt < NT; nt++) {
    float b = bias[nt * 16 + l15];
    int rowbase = w * 16 + quad * 4;
    #pragma unroll
    for (int r = 0; r < 4; r++) {
      float v = acc[nt][r] + b;
      v = v > 0.f ? v : 0.f;
      dst[(rowbase + r) * DSTR + nt * 16 + l15] = f2bf(v);
    }
  }
}

// bias (no relu) fp32 store to LN buffer (stride 65 floats, conflict-padded)
__device__ __forceinline__ void store_preln(f32x4 (&acc)[8], const float* __restrict__ bias,
                                            float* lnbuf, int w, int quad, int l15) {
  #pragma unroll
  for (int nt = 0; nt < 4; nt++) {
    float b = bias[nt * 16 + l15];
    #pragma unroll
    for (int r = 0; r < 4; r++)
      lnbuf[(w * 16 + quad * 4 + r) * 65 + nt * 16 + l15] = acc[nt][r] + b;
  }
}

// ---------------- message MLP kernel: 64 edges / block, 256 threads (4 waves) ----------------
__global__ __launch_bounds__(256, 4) void msg_kernel(
    const float* __restrict__ h, const int* __restrict__ ei, const float* __restrict__ ea,
    const unsigned short* __restrict__ wts,
    const float* __restrict__ mb1, const float* __restrict__ mb2, const float* __restrict__ mb3,
    const float* __restrict__ mg, const float* __restrict__ mbt,
    float* __restrict__ msg_out, float* __restrict__ agg, int E, int Nn) {
  // buf0 21504B: X(64x168 bf16) -> act2(64x136)
  // buf1 17408B: act1(64x136)   -> lnbuf(64x65 f32 = 16640)
  __shared__ __align__(16) unsigned char smem[21504 + 17408 + 512];
  unsigned short* buf0 = (unsigned short*)smem;
  unsigned short* buf1 = (unsigned short*)(smem + 21504);
  float* stats = (float*)(smem + 21504 + 17408);
  float* lnbuf = (float*)buf1;

  const int tid = threadIdx.x;
  const int w = tid >> 6, lane = tid & 63, quad = lane >> 4, l15 = lane & 15;
  const int e0 = blockIdx.x * 64;
  const int* srcI = ei;
  const int* dstI = ei + E;

  // ---- stage X = [h[src] | h[dst] | edge_attr] -> buf0 bf16, stride 168
  for (int idx = tid; idx < 64 * 40; idx += 256) {
    int er = idx / 40, seg = idx - er * 40;    // 40 float4 chunks per edge
    int e = e0 + er;
    u16x4 o = {0, 0, 0, 0};
    if (e < E) {
      const float* p;
      if (seg < 16)      p = h + (size_t)srcI[e] * 64 + seg * 4;
      else if (seg < 32) p = h + (size_t)dstI[e] * 64 + (seg - 16) * 4;
      else               p = ea + (size_t)e * 32 + (seg - 32) * 4;
      float4 v = *(const float4*)p;
      o[0] = f2bf(v.x); o[1] = f2bf(v.y); o[2] = f2bf(v.z); o[3] = f2bf(v.w);
    }
    *(u16x4*)&buf0[er * 168 + seg * 4] = o;
  }
  __syncthreads();

  f32x4 acc[8];
  // L1: 160 -> 128 (B from global, L1/L2-resident)
  do_layer<5, 8, 168, 160>(buf0, wts, acc, w, quad, l15);
  store_relu_bf16<8, 136>(acc, mb1, buf1, w, quad, l15);
  __syncthreads();
  // L2: 128 -> 128  (act1 in buf1 -> act2 in buf0; X dead)
  do_layer<4, 8, 136, 128>(buf1, wts + 20480, acc, w, quad, l15);
  store_relu_bf16<8, 136>(acc, mb2, buf0, w, quad, l15);
  __syncthreads();
  // L3: 128 -> 64 (no relu), fp32 -> lnbuf in buf1 (act1 dead)
  do_layer<4, 4, 136, 128>(buf0, wts + 36864, acc, w, quad, l15);
  store_preln(acc, mb3, lnbuf, w, quad, l15);
  __syncthreads();

  // ---- LayerNorm stats: one thread per row
  if (tid < 64) {
    float s = 0.f, sq = 0.f;
    #pragma unroll
    for (int c = 0; c < 64; c++) { float x = lnbuf[tid * 65 + c]; s += x; sq += x * x; }
    float mu = s * (1.f / 64.f);
    float var = sq * (1.f / 64.f) - mu * mu;
    stats[2 * tid] = mu;
    stats[2 * tid + 1] = rsqrtf(var + 1e-5f);
  }
  __syncthreads();

  // ---- write msg (float4, coalesced) + atomic scatter into agg[dst]
  for (int idx = tid; idx < 64 * 16; idx += 256) {
    int r = idx >> 4, c4 = (idx & 15) * 4;
    int e = e0 + r;
    if (e < E) {
      float mu = stats[2 * r], rstd = stats[2 * r + 1];
      int d = dstI[e];
      float4 o;
      float v0 = (lnbuf[r * 65 + c4 + 0] - mu) * rstd * mg[c4 + 0] + mbt[c4 + 0];
      float v1 = (lnbuf[r * 65 + c4 + 1] - mu) * rstd * mg[c4 + 1] + mbt[c4 + 1];
      float v2 = (lnbuf[r * 65 + c4 + 2] - mu) * rstd * mg[c4 + 2] + mbt[c4 + 2];
      float v3 = (lnbuf[r * 65 + c4 + 3] - mu) * rstd * mg[c4 + 3] + mbt[c4 + 3];
      o.x = v0; o.y = v1; o.z = v2; o.w = v3;
      *(float4*)&msg_out[(size_t)e * 64 + c4] = o;
      float* ap = agg + (size_t)d * 64 + c4;
      atomicAdd(ap + 0, v0);
      atomicAdd(ap + 1, v1);
      atomicAdd(ap + 2, v2);
      atomicAdd(ap + 3, v3);
    }
  }
}

// ---------------- update MLP kernel: 64 nodes / block, 256 threads ----------------
__global__ __launch_bounds__(256, 4) void upd_kernel(
    const float* __restrict__ h, const float* __restrict__ agg,
    const unsigned short* __restrict__ wts,
    const float* __restrict__ ub1, const float* __restrict__ ub2, const float* __restrict__ ub3,
    const float* __restrict__ ug, const float* __restrict__ ubt,
    float* __restrict__ h_new, int Nn) {
  // buf0 17408B: X(64x136) -> act2(64x136) ; buf1 17408B: act1 -> lnbuf
  __shared__ __align__(16) unsigned char smem[17408 + 17408 + 512];
  unsigned short* buf0 = (unsigned short*)smem;
  unsigned short* buf1 = (unsigned short*)(smem + 17408);
  float* stats = (float*)(smem + 17408 + 17408);
  float* lnbuf = (float*)buf1;

  const int tid = threadIdx.x;
  const int w = tid >> 6, lane = tid & 63, quad = lane >> 4, l15 = lane & 15;
  const int n0 = blockIdx.x * 64;

  // ---- stage X = [h | agg] -> buf0 bf16, stride 136
  for (int idx = tid; idx < 64 * 32; idx += 256) {
    int r = idx >> 5, seg = idx & 31;
    int n = n0 + r;
    u16x4 o = {0, 0, 0, 0};
    if (n < Nn) {
      const float* p = (seg < 16) ? h + (size_t)n * 64 + seg * 4
                                  : agg + (size_t)n * 64 + (seg - 16) * 4;
      float4 v = *(const float4*)p;
      o[0] = f2bf(v.x); o[1] = f2bf(v.y); o[2] = f2bf(v.z); o[3] = f2bf(v.w);
    }
    *(u16x4*)&buf0[r * 136 + seg * 4] = o;
  }
  __syncthreads();

  f32x4 acc[8];
  do_layer<4, 8, 136, 128>(buf0, wts + 45056, acc, w, quad, l15);
  store_relu_bf16<8, 136>(acc, ub1, buf1, w, quad, l15);
  __syncthreads();
  do_layer<4, 8, 136, 128>(buf1, wts + 61440, acc, w, quad, l15);
  store_relu_bf16<8, 136>(acc, ub2, buf0, w, quad, l15);
  __syncthreads();
  do_layer<4, 4, 136, 128>(buf0, wts + 77824, acc, w, quad, l15);
  store_preln(acc, ub3, lnbuf, w, quad, l15);
  __syncthreads();

  if (tid < 64) {
    float s = 0.f, sq = 0.f;
    #pragma unroll
    for (int c = 0; c < 64; c++) { float x = lnbuf[tid * 65 + c]; s += x; sq += x * x; }
    float mu = s * (1.f / 64.f);
    float var = sq * (1.f / 64.f) - mu * mu;
    stats[2 * tid] = mu;
    stats[2 * tid + 1] = rsqrtf(var + 1e-5f);
  }
  __syncthreads();

  for (int idx = tid; idx < 64 * 16; idx += 256) {
    int r = idx >> 4, c4 = (idx & 15) * 4;
    int n = n0 + r;
    if (n < Nn) {
      float mu = stats[2 * r], rstd = stats[2 * r + 1];
      const float* hp = h + (size_t)n * 64 + c4;
      float4 o;
      o.x = (lnbuf[r * 65 + c4 + 0] - mu) * rstd * ug[c4 + 0] + ubt[c4 + 0] + hp[0];
      o.y = (lnbuf[r * 65 + c4 + 1] - mu) * rstd * ug[c4 + 1] + ubt[c4 + 1] + hp[1];
      o.z = (lnbuf[r * 65 + c4 + 2] - mu) * rstd * ug[c4 + 2] + ubt[c4 + 2] + hp[2];
      o.w = (lnbuf[r * 65 + c4 + 3] - mu) * rstd * ug[c4 + 3] + ubt[c4 + 3] + hp[3];
      *(float4*)&h_new[(size_t)n * 64 + c4] = o;
    }
  }
}

extern "C" void kernel_launch(void* const* d_in, const int* in_sizes, int n_in,
                              void* d_out, int out_size, void* d_ws, size_t ws_size,
                              hipStream_t stream) {
  const float* h   = (const float*)d_in[0];
  const int*   ei  = (const int*)d_in[1];
  const float* ea  = (const float*)d_in[2];
  const float* mW1 = (const float*)d_in[3];
  const float* mb1 = (const float*)d_in[4];
  const float* mW2 = (const float*)d_in[5];
  const float* mb2 = (const float*)d_in[6];
  const float* mW3 = (const float*)d_in[7];
  const float* mb3 = (const float*)d_in[8];
  const float* mg  = (const float*)d_in[9];
  const float* mbt = (const float*)d_in[10];
  const float* uW1 = (const float*)d_in[11];
  const float* ub1 = (const float*)d_in[12];
  const float* uW2 = (const float*)d_in[13];
  const float* ub2 = (const float*)d_in[14];
  const float* uW3 = (const float*)d_in[15];
  const float* ub3 = (const float*)d_in[16];
  const float* ug  = (const float*)d_in[17];
  const float* ubt = (const float*)d_in[18];

  const int N = in_sizes[0] / 64;
  const int E = in_sizes[2] / 32;

  float* agg = (float*)d_ws;                                           // N*64 f32
  unsigned short* wts = (unsigned short*)((char*)d_ws + (size_t)N * 64 * sizeof(float));

  float* h_new = (float*)d_out;
  float* msg   = (float*)d_out + (size_t)N * 64;

  hipMemsetAsync(agg, 0, (size_t)N * 64 * sizeof(float), stream);
  wconv<<<dim3((86016 + 255) / 256), dim3(256), 0, stream>>>(mW1, mW2, mW3, uW1, uW2, uW3, wts);
  msg_kernel<<<dim3((E + 63) / 64), dim3(256), 0, stream>>>(
      h, ei, ea, wts, mb1, mb2, mb3, mg, mbt, msg, agg, E, N);
  upd_kernel<<<dim3((N + 63) / 64), dim3(256), 0, stream>>>(
      h, agg, wts, ub1, ub2, ub3, ug, ubt, h_new, N);
}